// Round 1
// baseline (33.114 us; speedup 1.0000x reference)
//
#include <hip/hip_runtime.h>
#include <math.h>

#define H_DIM 1024
#define N_DIM 64
#define L_DIM 2048
#define CHUNK 8
#define NTHREADS 256   // NTHREADS * CHUNK == L_DIM

__global__ __launch_bounds__(NTHREADS)
void lssl_kernel(const float* __restrict__ Lre, const float* __restrict__ Lim,
                 const float* __restrict__ Bre, const float* __restrict__ Bim,
                 const float* __restrict__ Cre, const float* __restrict__ Cim,
                 const float* __restrict__ Dv,  const float* __restrict__ log_dt,
                 float* __restrict__ out)
{
    const int h = blockIdx.x;
    const int t = threadIdx.x;

    // per-n parameters for this h:
    //  s_aw[n]  = (a_re, a_im, w_re, w_im)   with w = C * b_bar
    //  s_pol[n] = (ln|a|, arg(a)/2pi)
    __shared__ float4 s_aw[N_DIM];
    __shared__ float2 s_pol[N_DIM];

    if (t < N_DIM) {
        const int   n   = t;
        const int   idx = h * N_DIM + n;
        const float dt  = expf(log_dt[h]);
        const float lre = Lre[idx];
        const float lim = Lim[idx];
        // softplus(lre); lre in [0,1] so no overflow concerns
        const float sp  = log1pf(expf(lre));
        const float hr  = -0.5f * dt * sp;     // Re(half)
        const float hi  =  0.5f * dt * lim;    // Im(half)
        const float dr  = 1.0f - hr;           // denom = (dr, -hi)
        const float d2  = dr * dr + hi * hi;
        const float inv = 1.0f / d2;
        // a_bar = (1+half) * conj(denom) / |denom|^2 ; conj(denom) = (dr, +hi)
        const float xr  = 1.0f + hr;
        const float ar  = (xr * dr - hi * hi) * inv;
        const float ai  = 2.0f * hi * inv;
        // b_bar = (dt/denom) * B = dt*(dr, hi)*inv * (Br, Bi)
        const float tr  = dt * dr * inv;
        const float ti  = dt * hi * inv;
        const float bre = Bre[idx], bim = Bim[idx];
        const float br  = tr * bre - ti * bim;
        const float bi  = tr * bim + ti * bre;
        // w = C * b_bar
        const float cre = Cre[idx], cim = Cim[idx];
        const float wr  = cre * br - cim * bi;
        const float wi  = cre * bi + cim * br;

        const float m2   = ar * ar + ai * ai;
        const float lnA  = 0.5f * __logf(m2);                   // ln|a|
        const float thRv = atan2f(ai, ar) * 0.15915494309189535f; // arg/2pi

        s_aw[n]  = make_float4(ar, ai, wr, wi);
        s_pol[n] = make_float2(lnA, thRv);
    }
    __syncthreads();

    const float l0f = (float)(t * CHUNK);
    float acc[CHUNK];
#pragma unroll
    for (int j = 0; j < CHUNK; ++j) acc[j] = 0.0f;

#pragma unroll 2
    for (int n = 0; n < N_DIM; ++n) {
        const float4 aw  = s_aw[n];   // broadcast (all lanes same addr)
        const float2 pol = s_pol[n];
        // p = w * a^{l0} via polar form
        const float mag = __expf(l0f * pol.x);
        float rev = l0f * pol.y;
        rev -= floorf(rev);                 // reduce to [0,1) revolutions
        float s, c;
        __sincosf(rev * 6.283185307179586f, &s, &c);
        float pr = mag * (aw.z * c - aw.w * s);
        float pi = mag * (aw.z * s + aw.w * c);
#pragma unroll
        for (int j = 0; j < CHUNK; ++j) {
            acc[j] += pr;
            const float npr = pr * aw.x - pi * aw.y;
            pi = pr * aw.y + pi * aw.x;
            pr = npr;
        }
    }

    float* orow = out + (size_t)h * L_DIM + (size_t)t * CHUNK;
#pragma unroll
    for (int j = 0; j < CHUNK; ++j) orow[j] = acc[j];

    if (t == 0) out[(size_t)H_DIM * L_DIM + h] = Dv[h];
}

extern "C" void kernel_launch(void* const* d_in, const int* in_sizes, int n_in,
                              void* d_out, int out_size, void* d_ws, size_t ws_size,
                              hipStream_t stream) {
    const float* Lre   = (const float*)d_in[0];
    const float* Lim   = (const float*)d_in[1];
    const float* Bre   = (const float*)d_in[2];
    const float* Bim   = (const float*)d_in[3];
    const float* Cre   = (const float*)d_in[4];
    const float* Cim   = (const float*)d_in[5];
    const float* Dv    = (const float*)d_in[6];
    const float* logdt = (const float*)d_in[7];
    float* out = (float*)d_out;

    lssl_kernel<<<dim3(H_DIM), dim3(NTHREADS), 0, stream>>>(
        Lre, Lim, Bre, Bim, Cre, Cim, Dv, logdt, out);
}